// Round 1
// baseline (1742.627 us; speedup 1.0000x reference)
//
#include <hip/hip_runtime.h>

#define DT 0.1f

// Pack per-hidden-unit weights into one float4: (W1[0][j], W1[1][j], b1[j], W2[j])
__global__ void pack_weights(const float* __restrict__ W1, const float* __restrict__ b1,
                             const float* __restrict__ W2, float4* __restrict__ ws, int hidden) {
    int j = blockIdx.x * blockDim.x + threadIdx.x;
    if (j < hidden) {
        ws[j] = make_float4(W1[j], W1[hidden + j], b1[j], W2[j]);
    }
}

__global__ __launch_bounds__(256) void waterbalance(
    const float* __restrict__ inflows, const float* __restrict__ storage0,
    const float4* __restrict__ ws, const float* __restrict__ b2,
    float* __restrict__ out_storages, float* __restrict__ out_outflows,
    int iters, int batch, int hidden)
{
    int e = blockIdx.x * blockDim.x + threadIdx.x;
    if (e >= batch) return;

    float s = storage0[e];
    out_storages[e] = s;                 // storages[0] = storage0
    float b2v = b2[0];

    float inflow = inflows[e];           // t = 0
    for (int t = 0; t < iters; ++t) {
        // prefetch next step's inflow so the global load overlaps the inner loop
        float next = (t + 1 < iters) ? inflows[(size_t)(t + 1) * batch + e] : 0.0f;

        float acc0 = b2v, acc1 = 0.0f;   // split the accumulation dependency chain
        #pragma unroll 16
        for (int j = 0; j < hidden; j += 2) {
            float4 w0 = ws[j];
            float4 w1 = ws[j + 1];
            float z0 = fmaf(inflow, w0.x, fmaf(s, w0.y, w0.z));
            acc0 = fmaf(fmaxf(z0, 0.0f), w0.w, acc0);
            float z1 = fmaf(inflow, w1.x, fmaf(s, w1.y, w1.z));
            acc1 = fmaf(fmaxf(z1, 0.0f), w1.w, acc1);
        }
        float outflow = acc0 + acc1;
        s = fmaf(DT, inflow - outflow, s);

        out_outflows[(size_t)t * batch + e] = outflow;
        out_storages[(size_t)(t + 1) * batch + e] = s;

        inflow = next;
    }
}

extern "C" void kernel_launch(void* const* d_in, const int* in_sizes, int n_in,
                              void* d_out, int out_size, void* d_ws, size_t ws_size,
                              hipStream_t stream) {
    const float* inflows  = (const float*)d_in[0];
    const float* storage0 = (const float*)d_in[1];
    const float* W1       = (const float*)d_in[2];
    const float* b1       = (const float*)d_in[3];
    const float* W2       = (const float*)d_in[4];
    const float* b2       = (const float*)d_in[5];

    int batch  = in_sizes[1];                 // 65536
    int iters  = in_sizes[0] / batch;         // 512
    int hidden = in_sizes[3];                 // 256

    float4* ws = (float4*)d_ws;
    pack_weights<<<(hidden + 255) / 256, 256, 0, stream>>>(W1, b1, W2, ws, hidden);

    float* out_storages = (float*)d_out;                                // (iters+1, batch)
    float* out_outflows = out_storages + (size_t)(iters + 1) * batch;   // (iters, batch)

    waterbalance<<<(batch + 255) / 256, 256, 0, stream>>>(
        inflows, storage0, ws, b2, out_storages, out_outflows, iters, batch, hidden);
}

// Round 2
// 1059.187 us; speedup vs baseline: 1.6453x; 1.6453x over previous
//
#include <hip/hip_runtime.h>

#define DT 0.1f

typedef float v2f __attribute__((ext_vector_type(2)));

// Pack per-hidden-unit weights into one float4: (W1[0][j], W1[1][j], b1[j], W2[j])
__global__ void pack_weights(const float* __restrict__ W1, const float* __restrict__ b1,
                             const float* __restrict__ W2, float4* __restrict__ ws, int hidden) {
    int j = blockIdx.x * blockDim.x + threadIdx.x;
    if (j < hidden) {
        ws[j] = make_float4(W1[j], W1[hidden + j], b1[j], W2[j]);
    }
}

// DPP-based add-reduce helper (VALU pipe, no LDS/DS traffic).
// CTRL: 0xB1 = quad_perm(1,0,3,2) (xor 1); 0x4E = quad_perm(2,3,0,1) (xor 2);
//       0x141 = HALF_MIRROR (pairs lanes l <-> 7-l within each 8-lane group).
template <int CTRL>
__device__ __forceinline__ float dpp_add(float x) {
    int v = __builtin_amdgcn_mov_dpp(__float_as_int(x), CTRL, 0xf, 0xf, true);
    return x + __int_as_float(v);
}

// 8 lanes per element: p = lane & 7 owns hidden units [p*32, (p+1)*32).
// All weights live in registers (128 VGPRs/lane) -> zero steady-state weight traffic.
__global__ __launch_bounds__(256) void waterbalance(
    const float* __restrict__ inflows, const float* __restrict__ storage0,
    const float4* __restrict__ ws, const float* __restrict__ b2,
    float* __restrict__ out_storages, float* __restrict__ out_outflows,
    int iters, int batch)
{
    const int tid = blockIdx.x * blockDim.x + threadIdx.x;
    const int e = tid >> 3;      // element index
    const int p = tid & 7;       // unit-group within element
    if (e >= batch) return;

    // Load this lane's 32 units' weights into registers as float2 pairs.
    v2f wx[16], wy[16], wb[16], w2[16];
    #pragma unroll
    for (int r = 0; r < 16; ++r) {
        float4 a = ws[p * 32 + 2 * r];
        float4 b = ws[p * 32 + 2 * r + 1];
        wx[r] = (v2f){a.x, b.x};
        wy[r] = (v2f){a.y, b.y};
        wb[r] = (v2f){a.z, b.z};
        w2[r] = (v2f){a.w, b.w};
    }
    const float b2v = b2[0];

    float s = storage0[e];
    if (p == 0) out_storages[e] = s;     // storages[0] = storage0

    float inflow = inflows[e];           // t = 0
    for (int t = 0; t < iters; ++t) {
        // prefetch next step's inflow so the global load overlaps compute
        float next = (t + 1 < iters) ? inflows[(size_t)(t + 1) * batch + e] : 0.0f;

        const v2f in2 = (v2f){inflow, inflow};
        const v2f s2  = (v2f){s, s};
        v2f acc0 = (v2f)(0.0f);
        v2f acc1 = (v2f)(0.0f);
        const v2f zero2 = (v2f)(0.0f);

        #pragma unroll
        for (int r = 0; r < 16; r += 2) {
            v2f z0 = __builtin_elementwise_fma(in2, wx[r],
                        __builtin_elementwise_fma(s2, wy[r], wb[r]));
            z0 = __builtin_elementwise_max(z0, zero2);
            acc0 = __builtin_elementwise_fma(z0, w2[r], acc0);

            v2f z1 = __builtin_elementwise_fma(in2, wx[r + 1],
                        __builtin_elementwise_fma(s2, wy[r + 1], wb[r + 1]));
            z1 = __builtin_elementwise_max(z1, zero2);
            acc1 = __builtin_elementwise_fma(z1, w2[r + 1], acc1);
        }

        // per-lane partial -> sum over the 8 lanes of this element (VALU DPP tree)
        float part = (acc0.x + acc0.y) + (acc1.x + acc1.y);
        part = dpp_add<0xB1>(part);    // xor 1
        part = dpp_add<0x4E>(part);    // xor 2
        part = dpp_add<0x141>(part);   // quads A+B within 8-lane group
        const float outflow = part + b2v;

        s = fmaf(DT, inflow - outflow, s);   // identical in all 8 lanes

        if (p == 0) {
            out_outflows[(size_t)t * batch + e] = outflow;
            out_storages[(size_t)(t + 1) * batch + e] = s;
        }
        inflow = next;
    }
}

extern "C" void kernel_launch(void* const* d_in, const int* in_sizes, int n_in,
                              void* d_out, int out_size, void* d_ws, size_t ws_size,
                              hipStream_t stream) {
    const float* inflows  = (const float*)d_in[0];
    const float* storage0 = (const float*)d_in[1];
    const float* W1       = (const float*)d_in[2];
    const float* b1       = (const float*)d_in[3];
    const float* W2       = (const float*)d_in[4];
    const float* b2       = (const float*)d_in[5];

    int batch  = in_sizes[1];                 // 65536
    int iters  = in_sizes[0] / batch;         // 512
    int hidden = in_sizes[3];                 // 256

    float4* ws = (float4*)d_ws;
    pack_weights<<<(hidden + 255) / 256, 256, 0, stream>>>(W1, b1, W2, ws, hidden);

    float* out_storages = (float*)d_out;                                // (iters+1, batch)
    float* out_outflows = out_storages + (size_t)(iters + 1) * batch;   // (iters, batch)

    int threads = batch * 8;
    waterbalance<<<(threads + 255) / 256, 256, 0, stream>>>(
        inflows, storage0, ws, b2, out_storages, out_outflows, iters, batch);
}